// Round 10
// baseline (2694.635 us; speedup 1.0000x reference)
//
#include <hip/hip_runtime.h>

#define Bn  16
#define Ln  256
#define D0n 64
#define Hn  128
#define H4n 512
#define Kn  512
#define BLn 4096   // Bn*Ln

typedef float f4 __attribute__((ext_vector_type(4)));

__device__ __forceinline__ float sigf(float x) { return 1.0f / (1.0f + expf(-x)); }

__device__ __forceinline__ float fma4v(f4 w, f4 x, float acc) {
    acc = fmaf(w.x, x.x, acc);
    acc = fmaf(w.y, x.y, acc);
    acc = fmaf(w.z, x.z, acc);
    acc = fmaf(w.w, x.w, acc);
    return acc;
}

__device__ __forceinline__ float dotn(const f4* __restrict__ a,
                                      const f4* __restrict__ w, int n4) {
    float a0 = 0.f, a1 = 0.f, a2 = 0.f, a3 = 0.f;
    for (int i = 0; i < n4; i += 4) {
        a0 = fma4v(a[i], w[i], a0);
        a1 = fma4v(a[i + 1], w[i + 1], a1);
        a2 = fma4v(a[i + 2], w[i + 2], a2);
        a3 = fma4v(a[i + 3], w[i + 3], a3);
    }
    return (a0 + a1) + (a2 + a3);
}

// ---- tiled GEMM: Y[r][c] = scale*(X[r].W[c]) + b[c]; tiles 64r x 64c -------
__global__ __launch_bounds__(256)
void k_gemm(const float* __restrict__ X, const float* __restrict__ W,
            const float* __restrict__ b, float* __restrict__ Y,
            int K, int out_dim, int do_relu, float scale) {
    __shared__ f4 wt[4160];               // 64 x (K/4+1) max = 64x65
    const int K4 = K >> 2;
    const int st = K4 + 1;
    const int lg = __ffs(K4) - 1;
    const int tid = threadIdx.x;
    const int c = tid & 63, rpart = tid >> 6;
    const f4* W4 = (const f4*)W;
    const int per = (64 * K4) >> 8;       // K/16
    for (int i = 0; i < per; ++i) {
        int idx = i * 256 + tid;
        int row = idx >> lg, col = idx & (K4 - 1);
        wt[row * st + col] = W4[(size_t)(blockIdx.x * 64 + row) * K4 + col];
    }
    __syncthreads();
    const f4* X4 = (const f4*)X;
    const float bc = b ? b[blockIdx.x * 64 + c] : 0.f;
    const f4* wrow = wt + c * st;
    for (int i = 0; i < 16; ++i) {
        int r = blockIdx.y * 64 + i * 4 + rpart;
        const f4* xr = X4 + (size_t)r * K4;
        float a0 = 0.f, a1 = 0.f, a2 = 0.f, a3 = 0.f;
        for (int k = 0; k < K4; k += 4) {
            a0 = fma4v(wrow[k],     xr[k],     a0);
            a1 = fma4v(wrow[k + 1], xr[k + 1], a1);
            a2 = fma4v(wrow[k + 2], xr[k + 2], a2);
            a3 = fma4v(wrow[k + 3], xr[k + 3], a3);
        }
        float acc = scale * ((a0 + a1) + (a2 + a3)) + bc;
        if (do_relu) acc = fmaxf(acc, 0.f);
        Y[(size_t)r * out_dim + blockIdx.x * 64 + c] = acc;
    }
}

// -------- small transpose: out[c][r] = in[r][c] --------
__global__ void k_transpose(const float* __restrict__ in, float* __restrict__ out,
                            int R, int C) {
    int idx = blockIdx.x * blockDim.x + threadIdx.x;
    if (idx >= R * C) return;
    int c = idx / R, r = idx % R;
    out[idx] = in[(size_t)r * C + c];
}

__global__ void k_zero(int* __restrict__ p, int n) {
    int i = blockIdx.x * blockDim.x + threadIdx.x;
    if (i < n) p[i] = 0;
}

// ---- WihL[s][k][tid] = Wih[grow(s,tid)][half*16+k] (f4), lane-contiguous ----
__global__ void k_rearrWihL(const f4* __restrict__ in, f4* __restrict__ out) {
    int idx = blockIdx.x * blockDim.x + threadIdx.x;   // 16384
    if (idx >= 16384) return;
    int tid = idx & 255, k = (idx >> 8) & 15, s = idx >> 12;
    int r = tid >> 1, half = tid & 1;
    int grow = (r >> 5) * 128 + s * 32 + (r & 31);
    out[idx] = in[(size_t)grow * 32 + half * 16 + k];
}

// ---- KQL[(b*4+s)][k][tid] = kq[b*256+s*64+(tid>>2)][(tid&3)*8+k] (f4) ----
__global__ void k_rearrKQL(const f4* __restrict__ in, f4* __restrict__ out) {
    int idx = blockIdx.x * blockDim.x + threadIdx.x;   // 131072
    if (idx >= 131072) return;
    int tid = idx & 255, k = (idx >> 8) & 7, bs = idx >> 11;
    int row = (bs >> 2) * 256 + (bs & 3) * 64 + (tid >> 2);
    out[idx] = in[(size_t)row * 32 + (tid & 3) * 8 + k];
}

// -------- cst[p] = scale*(bq . kp[p]) + (mask[p]==0 ? -1e9 : 0) --------
__global__ void k_cst(const float* __restrict__ kp, const float* __restrict__ bq,
                      const float* __restrict__ mask, float* __restrict__ cst) {
    int p = blockIdx.x * blockDim.x + threadIdx.x;
    if (p >= BLn) return;
    float a = dotn((const f4*)bq, (const f4*)(kp + (size_t)p * Hn), Hn >> 2);
    cst[p] = a * 0.088388347648318447f + (mask[p] == 0.f ? -1e9f : 0.f);
}

// -------- codebook squared norms --------
__global__ void k_codenorm(const float* __restrict__ emb, float* __restrict__ c2) {
    int k = blockIdx.x * blockDim.x + threadIdx.x;
    if (k >= Kn) return;
    const f4* e4 = (const f4*)(emb + (size_t)k * Hn);
    float acc = 0.f;
    for (int i = 0; i < Hn / 4; ++i) {
        f4 v = e4[i];
        acc = fmaf(v.x, v.x, acc); acc = fmaf(v.y, v.y, acc);
        acc = fmaf(v.z, v.z, acc); acc = fmaf(v.w, v.w, acc);
    }
    c2[k] = acc;
}

// -------- VQ pick: argmin over dist row (first-index ties) + gather ---------
__global__ __launch_bounds__(128)
void k_vqpick(const float* __restrict__ dist, const float* __restrict__ emb,
              float* __restrict__ zq) {
    const int p = blockIdx.x, tid = threadIdx.x;
    __shared__ int best_s;
    if (tid < 64) {
        float best = 3.0e38f; int bi = 0;
        for (int j = 0; j < 8; ++j) {
            int k = j * 64 + tid;
            float d = dist[(size_t)p * Kn + k];
            if (d < best) { best = d; bi = k; }
        }
        for (int off = 32; off > 0; off >>= 1) {
            float ov = __shfl_xor(best, off);
            int   oi = __shfl_xor(bi, off);
            if (ov < best || (ov == best && oi < bi)) { best = ov; bi = oi; }
        }
        if (tid == 0) best_s = bi;
    }
    __syncthreads();
    zq[(size_t)p * Hn + tid] = emb[(size_t)best_s * Hn + tid];
}

// -------- LSTM: 2 blocks per (batch,dir) x 512 thr (unchanged from R9) ------
__global__ __launch_bounds__(512, 1)
void k_lstm2(const float* __restrict__ xWf, const float* __restrict__ xWb,
             const float* __restrict__ Whh_f, const float* __restrict__ Whh_b,
             float* __restrict__ hcat, float* gxl, int* flags) {
    const int b   = blockIdx.x & 15;
    const int dir = (blockIdx.x >> 4) & 1;
    const int hh  = blockIdx.x >> 5;          // partner = blockIdx ^ 32
    const int tid = threadIdx.x;
    const float* xW  = dir ? xWb : xWf;
    const float* Whh = dir ? Whh_b : Whh_f;

    __shared__ __align__(16) float h_s[Hn];
    __shared__ float g_loc[256];

    const int rl = tid >> 1, chalf = tid & 1;  // 256 rows x 2 threads
    const int grow = (rl >> 6) * 128 + hh * 64 + (rl & 63);

    f4 w[16];
    const f4* Whh4 = (const f4*)Whh;
#pragma unroll
    for (int f = 0; f < 16; ++f) w[f] = Whh4[(size_t)grow * 32 + chalf * 16 + f];
#pragma unroll
    for (int f = 0; f < 16; ++f) asm volatile("" : "+v"(w[f]));

    float c_reg = 0.f;
    if (tid < Hn) h_s[tid] = 0.f;

    float* gx_mine = gxl + ((b * 2 + dir) * 2 + hh) * 128;
    float* gx_peer = gxl + ((b * 2 + dir) * 2 + (hh ^ 1)) * 128;
    int* flag_mine = flags + (b * 4 + dir * 2 + hh) * 32;
    int* flag_peer = flags + (b * 4 + dir * 2 + (hh ^ 1)) * 32;

    const int t0 = dir ? (Ln - 1) : 0;
    float xw_v = (chalf == 0) ? xW[((size_t)b * Ln + t0) * H4n + grow] : 0.f;
    __syncthreads();

    for (int s = 0; s < Ln; ++s) {
        const int t = dir ? (Ln - 1 - s) : s;
        float xw_n = 0.f;
        if (chalf == 0 && s + 1 < Ln) {
            int tn = dir ? (Ln - 2 - s) : (s + 1);
            xw_n = xW[((size_t)b * Ln + tn) * H4n + grow];
        }
        {
            const f4* h4 = (const f4*)(h_s) + chalf * 16;
            float a0 = 0.f, a1 = 0.f, a2 = 0.f, a3 = 0.f;
#pragma unroll
            for (int f = 0; f < 16; f += 4) {
                a0 = fma4v(w[f],     h4[f],     a0);
                a1 = fma4v(w[f + 1], h4[f + 1], a1);
                a2 = fma4v(w[f + 2], h4[f + 2], a2);
                a3 = fma4v(w[f + 3], h4[f + 3], a3);
            }
            float a = (a0 + a1) + (a2 + a3);
            a += __shfl_xor(a, 1);
            if (chalf == 0) g_loc[rl] = a + xw_v;
        }
        __syncthreads();
        if (tid < 64) {
            float ig = sigf(g_loc[tid]);
            float fg = sigf(g_loc[64 + tid]);
            float gg = tanhf(g_loc[128 + tid]);
            float og = sigf(g_loc[192 + tid]);
            c_reg = fg * c_reg + ig * gg;
            float hv = og * tanhf(c_reg);
            int m = hh * 64 + tid;
            h_s[m] = hv;
            hcat[((size_t)b * Ln + t) * (2 * Hn) + dir * Hn + m] = hv;
            __hip_atomic_store(&gx_mine[(s & 1) * 64 + tid], hv,
                               __ATOMIC_RELAXED, __HIP_MEMORY_SCOPE_AGENT);
        }
        __syncthreads();   // drains vmcnt
        if (tid == 0) {
            __hip_atomic_store(flag_mine, s + 1, __ATOMIC_SEQ_CST, __HIP_MEMORY_SCOPE_AGENT);
            while (__hip_atomic_load(flag_peer, __ATOMIC_SEQ_CST, __HIP_MEMORY_SCOPE_AGENT) < s + 1) {}
        }
        __syncthreads();
        if (tid < 64)
            h_s[(hh ^ 1) * 64 + tid] =
                __hip_atomic_load(&gx_peer[(s & 1) * 64 + tid],
                                  __ATOMIC_RELAXED, __HIP_MEMORY_SCOPE_AGENT);
        __syncthreads();
        xw_v = xw_n;
    }
}

// -------- decoder: 4 blocks/batch x 256 thr, 128-VGPR-budget design ---------
// side s owns h[s*32,s*32+32) (gate rows q*128+s*32+j) and l in [s*64,s*64+64).
// Regs: whh half-row 64 + W1 slice 32 + bias = 97 (fits 128, no spill).
// LDS: Wih f4-major 64KB + KQ l-slice f4-major 32KB + VW (68-stride) 17KB.
// Attention via distributed partial-softmax: exchange (m,Z,P[64]) once.
__global__ __launch_bounds__(256, 1)
void k_decoder(const float* __restrict__ kqL_g, const float* __restrict__ vw_g,
               const float* __restrict__ cst_g,
               const float* __restrict__ W1,   const float* __restrict__ b1_g,
               const float* __restrict__ WihL_g, const float* __restrict__ Whh,
               const float* __restrict__ bd_g,
               float* gxh, float* gxp, int* fh, int* fs,
               float* __restrict__ dec_out, float* __restrict__ attn_w) {
    const int b   = blockIdx.x & 15;
    const int s   = blockIdx.x >> 4;      // {b, b+16, b+32, b+48} same XCD
    const int tid = threadIdx.x;

    __shared__ __align__(16) f4 wih_s[4096];       // [k<16][256] 64 KB
    __shared__ __align__(16) f4 kq_s[2048];        // [k<8][256]  32 KB
    __shared__ __align__(16) float vw_s[64 * 68];  // [l][o] pad 68
    __shared__ __align__(16) float tok_s[D0n];
    __shared__ __align__(16) float x_s[Hn];
    __shared__ __align__(16) float h_s[Hn];
    __shared__ float g_loc[Hn];
    __shared__ float s_loc[64];
    __shared__ float e_loc[64];
    __shared__ float pP[4 * 68];
    __shared__ float P_loc[64];
    __shared__ float peerP[3][68];
    __shared__ float mz_s[2];
    __shared__ float b1_s[Hn];
    __shared__ float cst_s[64];

    const int r = tid >> 1, half = tid & 1;        // 128 rows x 2 threads
    const int grow = (r >> 5) * 128 + s * 32 + (r & 31);

    // ---- pinned registers (fits 128 budget) ----
    const f4* Whh4 = (const f4*)Whh;
    f4 whh[16], w1r[8];
#pragma unroll
    for (int f = 0; f < 16; ++f) whh[f] = Whh4[(size_t)grow * 32 + half * 16 + f];
    const f4* W1_4 = (const f4*)W1;
#pragma unroll
    for (int k = 0; k < 8; ++k) w1r[k] = W1_4[(size_t)r * 16 + half * 8 + k];
    float bdr = bd_g[grow];
#pragma unroll
    for (int f = 0; f < 16; ++f) asm volatile("" : "+v"(whh[f]));
#pragma unroll
    for (int k = 0; k < 8; ++k) asm volatile("" : "+v"(w1r[k]));
    asm volatile("" : "+v"(bdr));

    // ---- stage LDS (all coalesced / lane-contiguous layouts) ----
    const f4* WihL4 = (const f4*)WihL_g;
#pragma unroll
    for (int it = 0; it < 16; ++it)
        wih_s[it * 256 + tid] = WihL4[(size_t)s * 4096 + it * 256 + tid];
    const f4* kqL4 = (const f4*)kqL_g;
#pragma unroll
    for (int it = 0; it < 8; ++it)
        kq_s[it * 256 + tid] = kqL4[(size_t)(b * 4 + s) * 2048 + it * 256 + tid];
    const f4* vw4 = (const f4*)(vw_g + ((size_t)b * Ln + s * 64) * D0n);
#pragma unroll
    for (int it = 0; it < 4; ++it) {
        int idx = it * 256 + tid;                  // 1024 f4
        int l = idx >> 4, c4 = idx & 15;
        *(f4*)&vw_s[l * 68 + c4 * 4] = vw4[idx];
    }
    if (tid < 64) cst_s[tid] = cst_g[(size_t)b * Ln + s * 64 + tid];
    if (tid < Hn) { h_s[tid] = 0.f; b1_s[tid] = b1_g[tid]; }
    if (tid < D0n) tok_s[tid] = 0.f;
    float c_reg = 0.f;
    __syncthreads();

    float* gxh_mine = gxh + (size_t)(b * 4 + s) * 2 * 32;
    float* gxp_mine = gxp + (size_t)(b * 4 + s) * 2 * 68;
    int* fh_mine = fh + (b * 4 + s) * 32;
    int* fs_mine = fs + (b * 4 + s) * 32;
    int* fh1 = fh + (b * 4 + ((s + 1) & 3)) * 32;
    int* fh2 = fh + (b * 4 + ((s + 2) & 3)) * 32;
    int* fh3 = fh + (b * 4 + ((s + 3) & 3)) * 32;
    int* fs1 = fs + (b * 4 + ((s + 1) & 3)) * 32;
    int* fs2 = fs + (b * 4 + ((s + 2) & 3)) * 32;
    int* fs3 = fs + (b * 4 + ((s + 3) & 3)) * 32;

    for (int t = 0; t < Ln; ++t) {
        // ---- A: x = relu(W1 @ tok + b1); 128 rows x 2 halves, W1 in regs ----
        {
            const f4* t4 = (const f4*)tok_s;
            float u0 = 0.f, u1 = 0.f;
#pragma unroll
            for (int k = 0; k < 8; k += 2) {
                u0 = fma4v(w1r[k],     t4[half * 8 + k],     u0);
                u1 = fma4v(w1r[k + 1], t4[half * 8 + k + 1], u1);
            }
            float a = u0 + u1;
            a += __shfl_xor(a, 1);
            if (half == 0) x_s[r] = fmaxf(a + b1_s[r], 0.f);
        }
        __syncthreads();
        // ---- B: gates; Wih from LDS (lane-contiguous), Whh from regs ----
        {
            const f4* x4 = (const f4*)x_s;
            const f4* h4 = (const f4*)h_s;
            const int hb = half * 16;
            float a0 = 0.f, a1 = 0.f, a2 = 0.f, a3 = 0.f;
#pragma unroll
            for (int f = 0; f < 16; f += 4) {
                a0 = fma4v(wih_s[f * 256 + tid],       x4[hb + f],     a0);
                a1 = fma4v(wih_s[(f + 1) * 256 + tid], x4[hb + f + 1], a1);
                a2 = fma4v(wih_s[(f + 2) * 256 + tid], x4[hb + f + 2], a2);
                a3 = fma4v(wih_s[(f + 3) * 256 + tid], x4[hb + f + 3], a3);
            }
#pragma unroll
            for (int f = 0; f < 16; f += 4) {
                a0 = fma4v(whh[f],     h4[hb + f],     a0);
                a1 = fma4v(whh[f + 1], h4[hb + f + 1], a1);
                a2 = fma4v(whh[f + 2], h4[hb + f + 2], a2);
                a3 = fma4v(whh[f + 3], h4[hb + f + 3], a3);
            }
            float a = (a0 + a1) + (a2 + a3);
            a += __shfl_xor(a, 1);
            if (half == 0) g_loc[r] = a + bdr;
        }
        __syncthreads();
        // ---- C: cell (own 32 comps) + publish h ----
        if (tid < 32) {
            float ig = sigf(g_loc[tid]);
            float fg = sigf(g_loc[32 + tid]);
            float gg = tanhf(g_loc[64 + tid]);
            float og = sigf(g_loc[96 + tid]);
            c_reg = fg * c_reg + ig * gg;
            float hv = og * tanhf(c_reg);
            h_s[s * 32 + tid] = hv;
            __hip_atomic_store(&gxh_mine[(t & 1) * 32 + tid], hv,
                               __ATOMIC_RELAXED, __HIP_MEMORY_SCOPE_AGENT);
        }
        __syncthreads();   // drain
        if (tid == 0) {
            __hip_atomic_store(fh_mine, t + 1, __ATOMIC_SEQ_CST, __HIP_MEMORY_SCOPE_AGENT);
            bool d1 = false, d2 = false, d3 = false;
            while (!(d1 && d2 && d3)) {
                if (!d1) d1 = __hip_atomic_load(fh1, __ATOMIC_SEQ_CST, __HIP_MEMORY_SCOPE_AGENT) > t;
                if (!d2) d2 = __hip_atomic_load(fh2, __ATOMIC_SEQ_CST, __HIP_MEMORY_SCOPE_AGENT) > t;
                if (!d3) d3 = __hip_atomic_load(fh3, __ATOMIC_SEQ_CST, __HIP_MEMORY_SCOPE_AGENT) > t;
            }
        }
        __syncthreads();
        if (tid < 96) {
            int spi = tid >> 5;
            int sp = spi + (spi >= s ? 1 : 0);
            int j = tid & 31;
            h_s[sp * 32 + j] = __hip_atomic_load(
                &gxh[((size_t)(b * 4 + sp) * 2 + (t & 1)) * 32 + j],
                __ATOMIC_RELAXED, __HIP_MEMORY_SCOPE_AGENT);
        }
        __syncthreads();
        // ---- D: own 64 scores; KQ lane-contiguous, 4 thr/l ----
        {
            const int l = tid >> 2, dp = tid & 3;
            const f4* h4 = (const f4*)h_s;
            float u0 = 0.f, u1 = 0.f;
#pragma unroll
            for (int k = 0; k < 8; k += 2) {
                u0 = fma4v(kq_s[k * 256 + tid],       h4[dp * 8 + k],     u0);
                u1 = fma4v(kq_s[(k + 1) * 256 + tid], h4[dp * 8 + k + 1], u1);
            }
            float a = u0 + u1;
            a += __shfl_xor(a, 1);
            a += __shfl_xor(a, 2);
            if (dp == 0) s_loc[l] = a + cst_s[l];
        }
        __syncthreads();
        // ---- preE: local max/sum over own 64 scores (wave 0) ----
        if (tid < 64) {
            float v = s_loc[tid];
            float m = v;
#pragma unroll
            for (int o2 = 32; o2 > 0; o2 >>= 1) m = fmaxf(m, __shfl_xor(m, o2));
            float e = expf(v - m);
            float Z = e;
#pragma unroll
            for (int o2 = 32; o2 > 0; o2 >>= 1) Z += __shfl_xor(Z, o2);
            e_loc[tid] = e;
            if (tid == 0) { mz_s[0] = m; mz_s[1] = Z; }
        }
        __syncthreads();
        // ---- E: partial P[o] = sum_{l in slice} e_l * VW[l][o]; 4 parts ----
        {
            const int p = tid >> 6, o = tid & 63;
            float acc = 0.f;
#pragma unroll
            for (int k = 0; k < 16; ++k)
                acc = fmaf(e_loc[p * 16 + k], vw_s[(p * 16 + k) * 68 + o], acc);
            pP[p * 68 + o] = acc;
        }
        __syncthreads();
        // ---- E2: combine parts, publish (P, m, Z) ----
        if (tid < 64) {
            float P = pP[tid] + pP[68 + tid] + pP[136 + tid] + pP[204 + tid];
            P_loc[tid] = P;
            __hip_atomic_store(&gxp_mine[(t & 1) * 68 + tid], P,
                               __ATOMIC_RELAXED, __HIP_MEMORY_SCOPE_AGENT);
        } else if (tid == 64) {
            __hip_atomic_store(&gxp_mine[(t & 1) * 68 + 64], mz_s[0],
                               __ATOMIC_RELAXED, __HIP_MEMORY_SCOPE_AGENT);
        } else if (tid == 65) {
            __hip_atomic_store(&gxp_mine[(t & 1) * 68 + 65], mz_s[1],
                               __ATOMIC_RELAXED, __HIP_MEMORY_SCOPE_AGENT);
        }
        __syncthreads();   // drain
        if (tid == 0) {
            __hip_atomic_store(fs_mine, t + 1, __ATOMIC_SEQ_CST, __HIP_MEMORY_SCOPE_AGENT);
            bool d1 = false, d2 = false, d3 = false;
            while (!(d1 && d2 && d3)) {
                if (!d1) d1 = __hip_atomic_load(fs1, __ATOMIC_SEQ_CST, __HIP_MEMORY_SCOPE_AGENT) > t;
                if (!d2) d2 = __hip_atomic_load(fs2, __ATOMIC_SEQ_CST, __HIP_MEMORY_SCOPE_AGENT) > t;
                if (!d3) d3 = __hip_atomic_load(fs3, __ATOMIC_SEQ_CST, __HIP_MEMORY_SCOPE_AGENT) > t;
            }
        }
        __syncthreads();
        if (tid < 204) {
            int spi = tid / 68, j = tid - spi * 68;
            int sp = spi + (spi >= s ? 1 : 0);
            peerP[spi][j] = __hip_atomic_load(
                &gxp[((size_t)(b * 4 + sp) * 2 + (t & 1)) * 68 + j],
                __ATOMIC_RELAXED, __HIP_MEMORY_SCOPE_AGENT);
        }
        __syncthreads();
        // ---- F: global combine; out + attn_w slice + next tok ----
        if (tid < 64) {
            float m0 = mz_s[0], Z0 = mz_s[1];
            float m1 = peerP[0][64], Z1 = peerP[0][65];
            float m2 = peerP[1][64], Z2 = peerP[1][65];
            float m3 = peerP[2][64], Z3 = peerP[2][65];
            float M = fmaxf(fmaxf(m0, m1), fmaxf(m2, m3));
            float w0 = expf(m0 - M), w1 = expf(m1 - M);
            float w2 = expf(m2 - M), w3 = expf(m3 - M);
            float inv = 1.f / (w0 * Z0 + w1 * Z1 + w2 * Z2 + w3 * Z3);
            float ov = (w0 * P_loc[tid] + w1 * peerP[0][tid]
                      + w2 * peerP[1][tid] + w3 * peerP[2][tid]) * inv;
            tok_s[tid] = ov;
            if (s == 0) dec_out[((size_t)b * Ln + t) * D0n + tid] = ov;
            attn_w[((size_t)b * Ln + t) * Ln + s * 64 + tid] = e_loc[tid] * w0 * inv;
        }
        __syncthreads();
    }
}

extern "C" void kernel_launch(void* const* d_in, const int* in_sizes, int n_in,
                              void* d_out, int out_size, void* d_ws, size_t ws_size,
                              hipStream_t stream) {
    const float* inputs     = (const float*)d_in[0];
    const float* in_mask    = (const float*)d_in[2];
    const float* enc_lin1_W = (const float*)d_in[3];
    const float* enc_lin1_b = (const float*)d_in[4];
    const float* enc_Wih_f  = (const float*)d_in[5];
    const float* enc_Whh_f  = (const float*)d_in[6];
    const float* enc_b_f    = (const float*)d_in[7];
    const float* enc_Wih_b  = (const float*)d_in[8];
    const float* enc_Whh_b  = (const float*)d_in[9];
    const float* enc_b_b    = (const float*)d_in[10];
    const float* enc_lin2_W = (const float*)d_in[11];
    const float* enc_lin2_b = (const float*)d_in[12];
    const float* vq_emb     = (const float*)d_in[13];
    const float* dec_lin1_W = (const float*)d_in[14];
    const float* dec_lin1_b = (const float*)d_in[15];
    const float* dec_Wih    = (const float*)d_in[16];
    const float* dec_Whh    = (const float*)d_in[17];
    const float* dec_b      = (const float*)d_in[18];
    const float* attn_Wq    = (const float*)d_in[19];
    const float* attn_bq    = (const float*)d_in[20];
    const float* attn_Wk    = (const float*)d_in[21];
    const float* attn_bk    = (const float*)d_in[22];
    const float* attn_Wv    = (const float*)d_in[23];
    const float* attn_bv    = (const float*)d_in[24];
    const float* dec_lin2_W = (const float*)d_in[25];
    const float* dec_lin2_b = (const float*)d_in[26];

    float* out     = (float*)d_out;
    float* dec_out = out;                       // 16*256*64   = 262144
    float* attn_w  = out + 262144;              // 16*256*256  = 1048576
    float* ze      = out + 1310720;             // 16*256*128  = 524288
    float* zq      = out + 1835008;             // 16*256*128  = 524288

    float* ws    = (float*)d_ws;
    float* enc_x = ws;                          // 524288
    float* xWf   = enc_x + 524288;              // 2097152
    float* xWb   = xWf + 2097152;               // 2097152
    float* hcat  = xWb + 2097152;               // 1048576
    float* kp    = hcat + 1048576;              // 524288
    float* vp    = kp + 524288;                 // 524288
    float* c2    = vp + 524288;                 // 512
    float* gxh   = c2 + 512;                    // 16*4*2*32  = 4096
    float* gxp   = gxh + 4096;                  // 16*4*2*68  = 8704
    float* gxl   = gxp + 8704;                  // 16*2*2*128 = 8192
    int*   flags = (int*)(gxl + 8192);          // 6144 ints: fh|fs|fl
    int*   fh    = flags;
    int*   fs    = flags + 2048;
    int*   fl    = flags + 4096;
    // aliases into dead regions:
    float* WqT   = enc_x;                       // 16384 (enc_x dead after xW GEMMs)
    float* WihL  = enc_x + 16384;               // 65536
    float* dist  = xWf;                         // 2097152 (dead after vqpick)
    float* KQL   = xWf;                         // 524288  (reuses dist region)
    float* kq    = xWb;                         // 524288  (xWb dead post-LSTM)
    float* vw    = xWb + 524288;                // 262144
    float* cst   = xWb + 786432;                // 4096

    dim3 blk(256);
    // ---- encoder front ----
    k_gemm<<<dim3(2, 64), blk, 0, stream>>>(inputs, enc_lin1_W, enc_lin1_b, enc_x, D0n, Hn, 1, 1.f);
    k_gemm<<<dim3(8, 64), blk, 0, stream>>>(enc_x, enc_Wih_f, enc_b_f, xWf, Hn, H4n, 0, 1.f);
    k_gemm<<<dim3(8, 64), blk, 0, stream>>>(enc_x, enc_Wih_b, enc_b_b, xWb, Hn, H4n, 0, 1.f);
    k_transpose<<<64, 256, 0, stream>>>(attn_Wq, WqT, Hn, Hn);
    k_rearrWihL<<<64, 256, 0, stream>>>((const f4*)dec_Wih, (f4*)WihL);
    k_zero<<<24, 256, 0, stream>>>(flags, 6144);
    // ---- BiLSTM: 64 blocks = 16b x 2dir x 2half ----
    k_lstm2<<<64, 512, 0, stream>>>(xWf, xWb, enc_Whh_f, enc_Whh_b, hcat, gxl, fl);
    k_gemm<<<dim3(2, 64), blk, 0, stream>>>(hcat, enc_lin2_W, enc_lin2_b, ze, 2 * Hn, Hn, 0, 1.f);
    // ---- VQ ----
    k_codenorm<<<2, 256, 0, stream>>>(vq_emb, c2);
    k_gemm<<<dim3(8, 64), blk, 0, stream>>>(ze, vq_emb, c2, dist, Hn, Kn, 0, -2.f);
    k_vqpick<<<BLn, 128, 0, stream>>>(dist, vq_emb, zq);
    // ---- attention precomputes (dec_in == zq) ----
    k_gemm<<<dim3(2, 64), blk, 0, stream>>>(zq, attn_Wk, attn_bk, kp, Hn, Hn, 0, 1.f);
    k_gemm<<<dim3(2, 64), blk, 0, stream>>>(zq, attn_Wv, attn_bv, vp, Hn, Hn, 0, 1.f);
    k_gemm<<<dim3(2, 64), blk, 0, stream>>>(kp, WqT, nullptr, kq, Hn, Hn, 0, 0.088388347648318447f);
    k_rearrKQL<<<512, 256, 0, stream>>>((const f4*)kq, (f4*)KQL);
    k_gemm<<<dim3(1, 64), blk, 0, stream>>>(vp, dec_lin2_W, dec_lin2_b, vw, Hn, D0n, 0, 1.f);
    k_cst<<<Bn, 256, 0, stream>>>(kp, attn_bq, in_mask, cst);
    // ---- decoder: 64 blocks = 16 batches x 4 sides, 256 thr ----
    k_decoder<<<64, 256, 0, stream>>>(KQL, vw, cst,
                                      dec_lin1_W, dec_lin1_b,
                                      WihL, dec_Whh, dec_b,
                                      gxh, gxp, fh, fs,
                                      dec_out, attn_w);
}

// Round 11
// 1599.381 us; speedup vs baseline: 1.6848x; 1.6848x over previous
//
#include <hip/hip_runtime.h>

#define Bn  16
#define Ln  256
#define D0n 64
#define Hn  128
#define H4n 512
#define Kn  512
#define BLn 4096   // Bn*Ln

typedef float f4 __attribute__((ext_vector_type(4)));
typedef unsigned long long u64;

__device__ __forceinline__ float sigf(float x) { return 1.0f / (1.0f + expf(-x)); }

__device__ __forceinline__ float fma4v(f4 w, f4 x, float acc) {
    acc = fmaf(w.x, x.x, acc);
    acc = fmaf(w.y, x.y, acc);
    acc = fmaf(w.z, x.z, acc);
    acc = fmaf(w.w, x.w, acc);
    return acc;
}

__device__ __forceinline__ float dotn(const f4* __restrict__ a,
                                      const f4* __restrict__ w, int n4) {
    float a0 = 0.f, a1 = 0.f, a2 = 0.f, a3 = 0.f;
    for (int i = 0; i < n4; i += 4) {
        a0 = fma4v(a[i], w[i], a0);
        a1 = fma4v(a[i + 1], w[i + 1], a1);
        a2 = fma4v(a[i + 2], w[i + 2], a2);
        a3 = fma4v(a[i + 3], w[i + 3], a3);
    }
    return (a0 + a1) + (a2 + a3);
}

// tagged-payload helpers: (tag<<32) | float bits, single 8B relaxed atomic
__device__ __forceinline__ void tag_store(u64* p, float v, unsigned tag) {
    u64 pk = ((u64)tag << 32) | (u64)__float_as_uint(v);
    __hip_atomic_store(p, pk, __ATOMIC_RELAXED, __HIP_MEMORY_SCOPE_AGENT);
}
__device__ __forceinline__ float tag_poll(u64* p, unsigned tag) {
    u64 v;
    do {
        v = __hip_atomic_load(p, __ATOMIC_RELAXED, __HIP_MEMORY_SCOPE_AGENT);
    } while ((unsigned)(v >> 32) != tag);
    return __uint_as_float((unsigned)v);
}

// ---- tiled GEMM: Y[r][c] = scale*(X[r].W[c]) + b[c]; tiles 64r x 64c -------
__global__ __launch_bounds__(256)
void k_gemm(const float* __restrict__ X, const float* __restrict__ W,
            const float* __restrict__ b, float* __restrict__ Y,
            int K, int out_dim, int do_relu, float scale) {
    __shared__ f4 wt[4160];               // 64 x (K/4+1) max = 64x65
    const int K4 = K >> 2;
    const int st = K4 + 1;
    const int lg = __ffs(K4) - 1;
    const int tid = threadIdx.x;
    const int c = tid & 63, rpart = tid >> 6;
    const f4* W4 = (const f4*)W;
    const int per = (64 * K4) >> 8;       // K/16
    for (int i = 0; i < per; ++i) {
        int idx = i * 256 + tid;
        int row = idx >> lg, col = idx & (K4 - 1);
        wt[row * st + col] = W4[(size_t)(blockIdx.x * 64 + row) * K4 + col];
    }
    __syncthreads();
    const f4* X4 = (const f4*)X;
    const float bc = b ? b[blockIdx.x * 64 + c] : 0.f;
    const f4* wrow = wt + c * st;
    for (int i = 0; i < 16; ++i) {
        int r = blockIdx.y * 64 + i * 4 + rpart;
        const f4* xr = X4 + (size_t)r * K4;
        float a0 = 0.f, a1 = 0.f, a2 = 0.f, a3 = 0.f;
        for (int k = 0; k < K4; k += 4) {
            a0 = fma4v(wrow[k],     xr[k],     a0);
            a1 = fma4v(wrow[k + 1], xr[k + 1], a1);
            a2 = fma4v(wrow[k + 2], xr[k + 2], a2);
            a3 = fma4v(wrow[k + 3], xr[k + 3], a3);
        }
        float acc = scale * ((a0 + a1) + (a2 + a3)) + bc;
        if (do_relu) acc = fmaxf(acc, 0.f);
        Y[(size_t)r * out_dim + blockIdx.x * 64 + c] = acc;
    }
}

// -------- small transpose: out[c][r] = in[r][c] --------
__global__ void k_transpose(const float* __restrict__ in, float* __restrict__ out,
                            int R, int C) {
    int idx = blockIdx.x * blockDim.x + threadIdx.x;
    if (idx >= R * C) return;
    int c = idx / R, r = idx % R;
    out[idx] = in[(size_t)r * C + c];
}

__global__ void k_zero(int* __restrict__ p, int n) {
    int i = blockIdx.x * blockDim.x + threadIdx.x;
    if (i < n) p[i] = 0;
}

// ---- WihL[k][side][tid] = Wih[grow][ (tid&1)*16 + k ], f4; k<16, tid<512 ----
// grow = ((tid>>1)>>6)*128 + side*64 + ((tid>>1)&63)  (quadrant split)
__global__ void k_rearrWihL2(const f4* __restrict__ in, f4* __restrict__ out) {
    int idx = blockIdx.x * blockDim.x + threadIdx.x;   // 16384
    if (idx >= 16384) return;
    int tid = idx & 511, side = (idx >> 9) & 1, k = idx >> 10;
    int rl = tid >> 1;
    int grow = (rl >> 6) * 128 + side * 64 + (rl & 63);
    out[idx] = in[(size_t)grow * 32 + (tid & 1) * 16 + k];
}

// ---- KQF[b][k][tid] = kq[b*256 + (tid>>1)][(tid&1)*16 + k], f4 ----
__global__ void k_rearrKQF(const f4* __restrict__ in, f4* __restrict__ out) {
    int idx = blockIdx.x * blockDim.x + threadIdx.x;   // 131072
    if (idx >= 131072) return;
    int tid = idx & 511, k = (idx >> 9) & 15, b = idx >> 13;
    out[idx] = in[((size_t)b * 256 + (tid >> 1)) * 32 + (tid & 1) * 16 + k];
}

// -------- cst[p] = scale*(bq . kp[p]) + (mask[p]==0 ? -1e9 : 0) --------
__global__ void k_cst(const float* __restrict__ kp, const float* __restrict__ bq,
                      const float* __restrict__ mask, float* __restrict__ cst) {
    int p = blockIdx.x * blockDim.x + threadIdx.x;
    if (p >= BLn) return;
    float a = dotn((const f4*)bq, (const f4*)(kp + (size_t)p * Hn), Hn >> 2);
    cst[p] = a * 0.088388347648318447f + (mask[p] == 0.f ? -1e9f : 0.f);
}

// -------- codebook squared norms --------
__global__ void k_codenorm(const float* __restrict__ emb, float* __restrict__ c2) {
    int k = blockIdx.x * blockDim.x + threadIdx.x;
    if (k >= Kn) return;
    const f4* e4 = (const f4*)(emb + (size_t)k * Hn);
    float acc = 0.f;
    for (int i = 0; i < Hn / 4; ++i) {
        f4 v = e4[i];
        acc = fmaf(v.x, v.x, acc); acc = fmaf(v.y, v.y, acc);
        acc = fmaf(v.z, v.z, acc); acc = fmaf(v.w, v.w, acc);
    }
    c2[k] = acc;
}

// -------- VQ pick: argmin over dist row (first-index ties) + gather ---------
__global__ __launch_bounds__(128)
void k_vqpick(const float* __restrict__ dist, const float* __restrict__ emb,
              float* __restrict__ zq) {
    const int p = blockIdx.x, tid = threadIdx.x;
    __shared__ int best_s;
    if (tid < 64) {
        float best = 3.0e38f; int bi = 0;
        for (int j = 0; j < 8; ++j) {
            int k = j * 64 + tid;
            float d = dist[(size_t)p * Kn + k];
            if (d < best) { best = d; bi = k; }
        }
        for (int off = 32; off > 0; off >>= 1) {
            float ov = __shfl_xor(best, off);
            int   oi = __shfl_xor(bi, off);
            if (ov < best || (ov == best && oi < bi)) { best = ov; bi = oi; }
        }
        if (tid == 0) best_s = bi;
    }
    __syncthreads();
    zq[(size_t)p * Hn + tid] = emb[(size_t)best_s * Hn + tid];
}

// -------- LSTM: 2 blocks per (batch,dir) x 512 thr; tagged exchange ---------
// block half hh owns comps [hh*64,hh*64+64); 2 barriers/step.
__global__ __launch_bounds__(512, 1)
void k_lstm2(const float* __restrict__ xWf, const float* __restrict__ xWb,
             const float* __restrict__ Whh_f, const float* __restrict__ Whh_b,
             float* __restrict__ hcat, u64* gxl) {
    const int b   = blockIdx.x & 15;
    const int dir = (blockIdx.x >> 4) & 1;
    const int hh  = blockIdx.x >> 5;          // partner = blockIdx ^ 32
    const int tid = threadIdx.x;
    const float* xW  = dir ? xWb : xWf;
    const float* Whh = dir ? Whh_b : Whh_f;

    __shared__ __align__(16) float h_s[Hn];
    __shared__ float g_loc[256];

    const int rl = tid >> 1, chalf = tid & 1;  // 256 rows x 2 threads
    const int grow = (rl >> 6) * 128 + hh * 64 + (rl & 63);

    f4 w[16];
    const f4* Whh4 = (const f4*)Whh;
#pragma unroll
    for (int f = 0; f < 16; ++f) w[f] = Whh4[(size_t)grow * 32 + chalf * 16 + f];
#pragma unroll
    for (int f = 0; f < 16; ++f) asm volatile("" : "+v"(w[f]));

    float c_reg = 0.f;
    if (tid < Hn) h_s[tid] = 0.f;

    u64* gx_mine = gxl + ((b * 2 + dir) * 2 + hh) * 128;
    u64* gx_peer = gxl + ((b * 2 + dir) * 2 + (hh ^ 1)) * 128;

    const int t0 = dir ? (Ln - 1) : 0;
    float xw_v = (chalf == 0) ? xW[((size_t)b * Ln + t0) * H4n + grow] : 0.f;
    __syncthreads();

    for (int s = 0; s < Ln; ++s) {
        const int t = dir ? (Ln - 1 - s) : s;
        float xw_n = 0.f;
        if (chalf == 0 && s + 1 < Ln) {
            int tn = dir ? (Ln - 2 - s) : (s + 1);
            xw_n = xW[((size_t)b * Ln + tn) * H4n + grow];
        }
        {
            const f4* h4 = (const f4*)(h_s) + chalf * 16;
            float a0 = 0.f, a1 = 0.f, a2 = 0.f, a3 = 0.f;
#pragma unroll
            for (int f = 0; f < 16; f += 4) {
                a0 = fma4v(w[f],     h4[f],     a0);
                a1 = fma4v(w[f + 1], h4[f + 1], a1);
                a2 = fma4v(w[f + 2], h4[f + 2], a2);
                a3 = fma4v(w[f + 3], h4[f + 3], a3);
            }
            float a = (a0 + a1) + (a2 + a3);
            a += __shfl_xor(a, 1);
            if (chalf == 0) g_loc[rl] = a + xw_v;
        }
        __syncthreads();
        if (tid < 64) {
            float ig = sigf(g_loc[tid]);
            float fg = sigf(g_loc[64 + tid]);
            float gg = tanhf(g_loc[128 + tid]);
            float og = sigf(g_loc[192 + tid]);
            c_reg = fg * c_reg + ig * gg;
            float hv = og * tanhf(c_reg);
            int m = hh * 64 + tid;
            h_s[m] = hv;
            hcat[((size_t)b * Ln + t) * (2 * Hn) + dir * Hn + m] = hv;
            tag_store(&gx_mine[(s & 1) * 64 + tid], hv, (unsigned)(s + 1));
            h_s[(hh ^ 1) * 64 + tid] =
                tag_poll(&gx_peer[(s & 1) * 64 + tid], (unsigned)(s + 1));
        }
        __syncthreads();
        xw_v = xw_n;
    }
}

// -------- decoder: 2 blocks/batch x 512 thr; tagged exchange; 6 barriers ----
// side owns gate rows {q*128+side*64+j} -> cell local for h[side*64..+64).
// Pinned: whh 16f4 (64) + vwr 32 + bdr = 97. Wih-half in LDS f4-major 128KB.
// W1, KQ streamed from L2 (pre-rearranged coalesced layouts).
__global__ __launch_bounds__(512, 1)
void k_decoder(const float* __restrict__ kqF_g, const float* __restrict__ vw_g,
               const float* __restrict__ cst_g,
               const float* __restrict__ W1,  const float* __restrict__ b1_g,
               const float* __restrict__ WihL_g, const float* __restrict__ Whh,
               const float* __restrict__ bd_g, u64* gxd,
               float* __restrict__ dec_out, float* __restrict__ attn_w) {
    const int b    = blockIdx.x & 15;
    const int side = blockIdx.x >> 4;     // b and b+16 same XCD (round-robin %8)
    const int tid  = threadIdx.x;

    __shared__ __align__(16) f4 wih_s[16 * 512];   // 128 KB, lane-contiguous
    __shared__ __align__(16) float tok_s[D0n];
    __shared__ __align__(16) float x_s[Hn];
    __shared__ __align__(16) float h_s[Hn];
    __shared__ float g_loc[256];
    __shared__ float s_s[Ln];
    __shared__ float attn_sp[8][33];               // padded (slab-major)
    __shared__ float cst_s[Ln];
    __shared__ float b1_s[Hn];

    const int rl = tid >> 1, ghalf = tid & 1;      // gates: 256 rows x 2 thr
    const int grow = (rl >> 6) * 128 + side * 64 + (rl & 63);

    // ---- pinned: whh half-row + VW slice + bias ----
    const f4* Whh4 = (const f4*)Whh;
    f4 whh[16];
#pragma unroll
    for (int f = 0; f < 16; ++f) whh[f] = Whh4[(size_t)grow * 32 + ghalf * 16 + f];
    float bdr = bd_g[grow];
    const int o = tid >> 3, slab = tid & 7;        // out phase map
    float vwr[32];
#pragma unroll
    for (int l = 0; l < 32; ++l)
        vwr[l] = vw_g[((size_t)b * Ln + slab * 32 + l) * D0n + o];
#pragma unroll
    for (int f = 0; f < 16; ++f) asm volatile("" : "+v"(whh[f]));
#pragma unroll
    for (int l = 0; l < 32; ++l) asm volatile("" : "+v"(vwr[l]));
    asm volatile("" : "+v"(bdr));

    // ---- stage Wih-half into LDS (coalesced both ends) ----
    const f4* WihL4 = (const f4*)WihL_g;
#pragma unroll
    for (int k = 0; k < 16; ++k)
        wih_s[k * 512 + tid] = WihL4[(size_t)k * 1024 + side * 512 + tid];
    if (tid < D0n) tok_s[tid] = 0.f;
    if (tid < Hn)  { h_s[tid] = 0.f; b1_s[tid] = b1_g[tid]; }
    if (tid < Ln)  cst_s[tid] = cst_g[(size_t)b * Ln + tid];
    float c_reg = 0.f;
    __syncthreads();

    u64* gx_mine = gxd + (b * 2 + side) * 128;
    u64* gx_peer = gxd + (b * 2 + (side ^ 1)) * 128;

    const int ar = tid >> 2, ap = tid & 3;         // x phase: 128 rows x 4 thr
    const f4* W1_4 = (const f4*)W1;
    const f4* kqF  = (const f4*)kqF_g + (size_t)b * 8192;
    const int dbase = (tid & 1) * 16;              // score phase h offset

    for (int t = 0; t < Ln; ++t) {
        // ---- A: x = relu(W1 @ tok + b1); W1 streamed (L2-hot) ----
        {
            const f4* t4 = (const f4*)tok_s;
            float u0 = 0.f, u1 = 0.f;
#pragma unroll
            for (int k = 0; k < 4; k += 2) {
                f4 wa = W1_4[(size_t)ar * 16 + ap * 4 + k];
                f4 wb2 = W1_4[(size_t)ar * 16 + ap * 4 + k + 1];
                u0 = fma4v(wa,  t4[ap * 4 + k],     u0);
                u1 = fma4v(wb2, t4[ap * 4 + k + 1], u1);
            }
            float a = u0 + u1;
            a += __shfl_xor(a, 1);
            a += __shfl_xor(a, 2);
            if (ap == 0) x_s[ar] = fmaxf(a + b1_s[ar], 0.f);
        }
        __syncthreads();
        // ---- B: gates; Wih from LDS (lane-contig), Whh pinned ----
        {
            const f4* x4 = (const f4*)x_s + ghalf * 16;
            const f4* h4 = (const f4*)h_s + ghalf * 16;
            float a0 = 0.f, a1 = 0.f, a2 = 0.f, a3 = 0.f;
#pragma unroll
            for (int f = 0; f < 16; f += 4) {
                a0 = fma4v(wih_s[f * 512 + tid],       x4[f],     a0);
                a1 = fma4v(wih_s[(f + 1) * 512 + tid], x4[f + 1], a1);
                a2 = fma4v(wih_s[(f + 2) * 512 + tid], x4[f + 2], a2);
                a3 = fma4v(wih_s[(f + 3) * 512 + tid], x4[f + 3], a3);
            }
#pragma unroll
            for (int f = 0; f < 16; f += 4) {
                a0 = fma4v(whh[f],     h4[f],     a0);
                a1 = fma4v(whh[f + 1], h4[f + 1], a1);
                a2 = fma4v(whh[f + 2], h4[f + 2], a2);
                a3 = fma4v(whh[f + 3], h4[f + 3], a3);
            }
            float a = (a0 + a1) + (a2 + a3);
            a += __shfl_xor(a, 1);
            if (ghalf == 0) g_loc[rl] = a + bdr;
        }
        __syncthreads();
        // ---- C: cell (own 64) + tagged publish + poll peer (fused) ----
        if (tid < 64) {
            float ig = sigf(g_loc[tid]);
            float fg = sigf(g_loc[64 + tid]);
            float gg = tanhf(g_loc[128 + tid]);
            float og = sigf(g_loc[192 + tid]);
            c_reg = fg * c_reg + ig * gg;
            float hv = og * tanhf(c_reg);
            h_s[side * 64 + tid] = hv;
            tag_store(&gx_mine[(t & 1) * 64 + tid], hv, (unsigned)(t + 1));
            h_s[(side ^ 1) * 64 + tid] =
                tag_poll(&gx_peer[(t & 1) * 64 + tid], (unsigned)(t + 1));
        }
        __syncthreads();
        // ---- D: scores; KQ streamed coalesced from L2 (L2-hot) ----
        {
            const f4* h4 = (const f4*)h_s;
            float a0 = 0.f, a1 = 0.f;
#pragma unroll
            for (int k = 0; k < 16; k += 2) {
                f4 q0 = kqF[(size_t)k * 512 + tid];
                f4 q1 = kqF[(size_t)(k + 1) * 512 + tid];
                a0 = fma4v(q0, h4[dbase + k],     a0);
                a1 = fma4v(q1, h4[dbase + k + 1], a1);
            }
            float a = a0 + a1;
            a += __shfl_xor(a, 1);
            if (ghalf == 0) s_s[rl] = a + cst_s[rl];
        }
        __syncthreads();
        // ---- E: softmax (wave 0); side 0 writes attn_w ----
        if (tid < 64) {
            float v0 = s_s[tid],       v1 = s_s[tid + 64];
            float v2 = s_s[tid + 128], v3 = s_s[tid + 192];
            float m = fmaxf(fmaxf(v0, v1), fmaxf(v2, v3));
#pragma unroll
            for (int o2 = 32; o2 > 0; o2 >>= 1) m = fmaxf(m, __shfl_xor(m, o2));
            float e0 = expf(v0 - m), e1 = expf(v1 - m);
            float e2 = expf(v2 - m), e3 = expf(v3 - m);
            float ss = (e0 + e1) + (e2 + e3);
#pragma unroll
            for (int o2 = 32; o2 > 0; o2 >>= 1) ss += __shfl_xor(ss, o2);
            float inv = 1.f / ss;
            e0 *= inv; e1 *= inv; e2 *= inv; e3 *= inv;
            attn_sp[tid >> 5][tid & 31] = e0;
            attn_sp[(tid + 64) >> 5][tid & 31] = e1;
            attn_sp[(tid + 128) >> 5][tid & 31] = e2;
            attn_sp[(tid + 192) >> 5][tid & 31] = e3;
            if (side == 0) {
                float* aw = attn_w + ((size_t)b * Ln + t) * Ln;
                aw[tid] = e0; aw[tid + 64] = e1;
                aw[tid + 128] = e2; aw[tid + 192] = e3;
            }
        }
        __syncthreads();
        // ---- F: out[o] = sum_l attn[l]*VW'[l][o]; 64 o x 8 slabs ----
        {
            const float* as = attn_sp[slab];
            float g0 = 0.f, g1 = 0.f, g2 = 0.f, g3 = 0.f;
#pragma unroll
            for (int l = 0; l < 32; l += 4) {
                g0 = fmaf(as[l],     vwr[l],     g0);
                g1 = fmaf(as[l + 1], vwr[l + 1], g1);
                g2 = fmaf(as[l + 2], vwr[l + 2], g2);
                g3 = fmaf(as[l + 3], vwr[l + 3], g3);
            }
            float a = (g0 + g1) + (g2 + g3);
            a += __shfl_xor(a, 1);
            a += __shfl_xor(a, 2);
            a += __shfl_xor(a, 4);
            if (slab == 0) {
                tok_s[o] = a;
                if (side == 1) dec_out[((size_t)b * Ln + t) * D0n + o] = a;
            }
        }
        __syncthreads();
    }
}

extern "C" void kernel_launch(void* const* d_in, const int* in_sizes, int n_in,
                              void* d_out, int out_size, void* d_ws, size_t ws_size,
                              hipStream_t stream) {
    const float* inputs     = (const float*)d_in[0];
    const float* in_mask    = (const float*)d_in[2];
    const float* enc_lin1_W = (const float*)d_in[3];
    const float* enc_lin1_b = (const float*)d_in[4];
    const float* enc_Wih_f  = (const float*)d_in[5];
    const float* enc_Whh_f  = (const float*)d_in[6];
    const float* enc_b_f    = (const float*)d_in[7];
    const float* enc_Wih_b  = (const float*)d_in[8];
    const float* enc_Whh_b  = (const float*)d_in[9];
    const float* enc_b_b    = (const float*)d_in[10];
    const float* enc_lin2_W = (const float*)d_in[11];
    const float* enc_lin2_b = (const float*)d_in[12];
    const float* vq_emb     = (const float*)d_in[13];
    const float* dec_lin1_W = (const float*)d_in[14];
    const float* dec_lin1_b = (const float*)d_in[15];
    const float* dec_Wih    = (const float*)d_in[16];
    const float* dec_Whh    = (const float*)d_in[17];
    const float* dec_b      = (const float*)d_in[18];
    const float* attn_Wq    = (const float*)d_in[19];
    const float* attn_bq    = (const float*)d_in[20];
    const float* attn_Wk    = (const float*)d_in[21];
    const float* attn_bk    = (const float*)d_in[22];
    const float* attn_Wv    = (const float*)d_in[23];
    const float* attn_bv    = (const float*)d_in[24];
    const float* dec_lin2_W = (const float*)d_in[25];
    const float* dec_lin2_b = (const float*)d_in[26];

    float* out     = (float*)d_out;
    float* dec_out = out;                       // 16*256*64   = 262144
    float* attn_w  = out + 262144;              // 16*256*256  = 1048576
    float* ze      = out + 1310720;             // 16*256*128  = 524288
    float* zq      = out + 1835008;             // 16*256*128  = 524288

    float* ws    = (float*)d_ws;
    float* enc_x = ws;                          // 524288
    float* xWf   = enc_x + 524288;              // 2097152
    float* xWb   = xWf + 2097152;               // 2097152
    float* hcat  = xWb + 2097152;               // 1048576
    float* kp    = hcat + 1048576;              // 524288
    float* vp    = kp + 524288;                 // 524288
    float* c2    = vp + 524288;                 // 512
    u64*   gxl   = (u64*)(c2 + 512);            // 64 units * 128 u64 = 8192 u64
    u64*   gxd   = gxl + 8192;                  // 32 units * 128 u64 = 4096 u64
    // (12288 u64 = 24576 ints of tag space, zeroed each launch)
    // aliases into dead regions:
    float* WqT   = enc_x;                       // 16384 (enc_x dead after xW GEMMs)
    float* WihL  = enc_x + 16384;               // 65536 floats = 16384 f4
    float* dist  = xWf;                         // 2097152 (dead after vqpick)
    float* KQF   = xWf;                         // 131072 f4 = 524288 floats
    float* kq    = xWb;                         // 524288  (xWb dead post-LSTM)
    float* vw    = xWb + 524288;                // 262144
    float* cst   = xWb + 786432;                // 4096

    dim3 blk(256);
    // ---- encoder front ----
    k_gemm<<<dim3(2, 64), blk, 0, stream>>>(inputs, enc_lin1_W, enc_lin1_b, enc_x, D0n, Hn, 1, 1.f);
    k_gemm<<<dim3(8, 64), blk, 0, stream>>>(enc_x, enc_Wih_f, enc_b_f, xWf, Hn, H4n, 0, 1.f);
    k_gemm<<<dim3(8, 64), blk, 0, stream>>>(enc_x, enc_Wih_b, enc_b_b, xWb, Hn, H4n, 0, 1.f);
    k_transpose<<<64, 256, 0, stream>>>(attn_Wq, WqT, Hn, Hn);
    k_rearrWihL2<<<64, 256, 0, stream>>>((const f4*)dec_Wih, (f4*)WihL);
    k_zero<<<96, 256, 0, stream>>>((int*)gxl, 24576);
    // ---- BiLSTM: 64 blocks = 16b x 2dir x 2half, tagged exchange ----
    k_lstm2<<<64, 512, 0, stream>>>(xWf, xWb, enc_Whh_f, enc_Whh_b, hcat, gxl);
    k_gemm<<<dim3(2, 64), blk, 0, stream>>>(hcat, enc_lin2_W, enc_lin2_b, ze, 2 * Hn, Hn, 0, 1.f);
    // ---- VQ ----
    k_codenorm<<<2, 256, 0, stream>>>(vq_emb, c2);
    k_gemm<<<dim3(8, 64), blk, 0, stream>>>(ze, vq_emb, c2, dist, Hn, Kn, 0, -2.f);
    k_vqpick<<<BLn, 128, 0, stream>>>(dist, vq_emb, zq);
    // ---- attention precomputes (dec_in == zq) ----
    k_gemm<<<dim3(2, 64), blk, 0, stream>>>(zq, attn_Wk, attn_bk, kp, Hn, Hn, 0, 1.f);
    k_gemm<<<dim3(2, 64), blk, 0, stream>>>(zq, attn_Wv, attn_bv, vp, Hn, Hn, 0, 1.f);
    k_gemm<<<dim3(2, 64), blk, 0, stream>>>(kp, WqT, nullptr, kq, Hn, Hn, 0, 0.088388347648318447f);
    k_rearrKQF<<<512, 256, 0, stream>>>((const f4*)kq, (f4*)KQF);
    k_gemm<<<dim3(1, 64), blk, 0, stream>>>(vp, dec_lin2_W, dec_lin2_b, vw, Hn, D0n, 0, 1.f);
    k_cst<<<Bn, 256, 0, stream>>>(kp, attn_bq, in_mask, cst);
    // ---- decoder: 32 blocks = 16 batches x 2 sides, 512 thr ----
    k_decoder<<<32, 512, 0, stream>>>(KQF, vw, cst,
                                      dec_lin1_W, dec_lin1_b,
                                      WihL, dec_Whh, dec_b, gxd,
                                      dec_out, attn_w);
}